// Round 9
// baseline (5331.126 us; speedup 1.0000x reference)
//
#include <hip/hip_runtime.h>
#include <math.h>

#define Bsz 16384
#define Msz 512
#define Nsz 2048

typedef _Float16 half8 __attribute__((ext_vector_type(8)));
typedef _Float16 half4 __attribute__((ext_vector_type(4)));
typedef float floatx16 __attribute__((ext_vector_type(16)));
typedef unsigned int uint;

// fragment-permuted layout (32x32x16 MFMA), lane-linear (bank-conflict-free):
// element (r,k) of [R][K] at frag((r>>5)*(K/16) + (k>>4))*512
//                          + ((k>>3)&1)*256 + (r&31)*8 + (k&7)      [halves]
// lane l's half8 A/B operand sits at frag*512 + l*8 -> 1KB contiguous per wave.

// One-time: D [M][N] fp32 -> Dph  (gemm2 B: r=m, k=n, K=2048, frag stride 128)
//                        and Dtph (gemm1 B: r=n, k=m, K=512,  frag stride 32)
__global__ __launch_bounds__(256) void convD_kernel(const float* __restrict__ D,
        _Float16* __restrict__ Dph, _Float16* __restrict__ Dtph) {
    __shared__ float T[64][65];
    const int t = threadIdx.x;
    const int tx = t & 15, ty = t >> 4;
    const int n0 = blockIdx.x << 6, m0 = blockIdx.y << 6;
#pragma unroll
    for (int q = 0; q < 4; ++q) {
        const int mr = m0 + (ty << 2) + q;
        const int nc = n0 + (tx << 2);
        float4 d = *(const float4*)(D + (size_t)mr * Nsz + nc);
        half4 h;
        h[0] = (_Float16)d.x; h[1] = (_Float16)d.y;
        h[2] = (_Float16)d.z; h[3] = (_Float16)d.w;
        const size_t o2 = ((size_t)(mr >> 5) * 128 + (nc >> 4)) * 512
                        + (((size_t)(nc >> 3) & 1) << 8) + ((mr & 31) << 3) + (nc & 7);
        *(half4*)(Dph + o2) = h;
        T[(tx << 2) + 0][(ty << 2) + q] = d.x;
        T[(tx << 2) + 1][(ty << 2) + q] = d.y;
        T[(tx << 2) + 2][(ty << 2) + q] = d.z;
        T[(tx << 2) + 3][(ty << 2) + q] = d.w;
    }
    __syncthreads();
#pragma unroll
    for (int q = 0; q < 4; ++q) {
        const int nr = n0 + (ty << 2) + q;
        const int mc = m0 + (tx << 2);
        float4 d = make_float4(T[(ty << 2) + q][tx << 2],
                               T[(ty << 2) + q][(tx << 2) + 1],
                               T[(ty << 2) + q][(tx << 2) + 2],
                               T[(ty << 2) + q][(tx << 2) + 3]);
        half4 h;
        h[0] = (_Float16)d.x; h[1] = (_Float16)d.y;
        h[2] = (_Float16)d.z; h[3] = (_Float16)d.w;
        const size_t o1 = ((size_t)(nr >> 5) * 32 + (mc >> 4)) * 512
                        + (((size_t)(mc >> 3) & 1) << 8) + ((nr & 31) << 3) + (mc & 7);
        *(half4*)(Dtph + o1) = h;
    }
}

// Fused persistent AMP kernel: each block owns 32 batch rows and runs ALL 10
// iterations. State: z (= alpha, fp32) in regs (4 x floatx16/thread, 16 waves);
// v as f16(beta*v) in LDS (A-frag layout, K=512); alpha operand as f16(-beta*z)
// in a 64KB LDS half-window (A-frag layout, K=2048, two halves per iteration);
// t2s/na2 per-row scalars in LDS. Zero alpha/v global traffic; no atomics to
// global; only global reads are D planes (L2) and y (L3), writes = final alpha.
// Scaling tricks: v stored pre-scaled by beta  -> gemm1 MFMA accumulates
// directly into z (z' = z + (bv)@Dt = z + b*(v@Dt));   alpha stored as -beta*z
// -> gemm2 MFMA accumulates into C=y+cb'*(bv_old), giving v_new directly.
__global__ __launch_bounds__(1024, 4) void amp_kernel(
        const float* __restrict__ y,
        const _Float16* __restrict__ Dt,    // gemm1 B plane (frag stride 32)
        const _Float16* __restrict__ Dp,    // gemm2 B plane (frag stride 128)
        const float* __restrict__ beta_p,
        const float* __restrict__ gamma_p,
        float* __restrict__ out) {
    __shared__ _Float16 alpha_lds[32768];   // 64KB: ktile half-window (64 frags)
    __shared__ _Float16 v_lds[16384];       // 32KB: 32 frags (K=512)
    __shared__ float t2s[32];               // ||beta*v||^2 per row
    __shared__ float na2[32];               // ||alpha||^2 per row

    const int tid = threadIdx.x;
    const int w = tid >> 6;                 // wave 0..15; owns n [128w,128w+128)
    const int lane = tid & 63;
    const int ln = lane & 31, lh = lane >> 5;
    const int b0 = blockIdx.x << 5;         // 32 rows per block, grid 512

    const float beta = beta_p[0];
    const float tcoef = gamma_p[0] * 0.044194173824159216f / beta; // g/sqrt(512)/b

    // ---- init: v0 = y; v_lds = f16(beta*y); t2s = sum (beta*y)^2; na2 = 0
    if (tid < 32) na2[tid] = 0.f;
    {
        const int b = tid >> 5, mg = tid & 31;     // 32 b-rows x 32 m-groups
        const float* yr = y + (size_t)(b0 + b) * Msz + mg * 16;
        float s = 0.f;
#pragma unroll
        for (int u4 = 0; u4 < 4; ++u4) {
            float4 f = *(const float4*)(yr + u4 * 4);
            float vals[4] = {f.x, f.y, f.z, f.w};
#pragma unroll
            for (int e = 0; e < 4; ++e) {
                float bv = beta * vals[e];
                s = fmaf(bv, bv, s);
                const int m = mg * 16 + u4 * 4 + e;
                v_lds[(m >> 4) * 512 + ((m >> 3) & 1) * 256 + b * 8 + (m & 7)] =
                    (_Float16)bv;
            }
        }
#pragma unroll
        for (int off = 16; off > 0; off >>= 1) s += __shfl_down(s, off, 32);
        if (mg == 0) t2s[b] = s;
    }
    __syncthreads();

    floatx16 z[4] = {};   // z[s][reg] = alpha(b = rr(reg,lh), n = 128w+32s+ln)

    for (int it = 0; it < 10; ++it) {
        // ---- gemm1: z += (beta*v) @ Dt   (K=512, 32 ktiles, 4 MFMA/kt/wave)
        for (int kt = 0; kt < 32; ++kt) {
            half8 A = *(const half8*)(v_lds + kt * 512 + lane * 8);
            half8 Bf[4];
#pragma unroll
            for (int s = 0; s < 4; ++s)
                Bf[s] = *(const half8*)(Dt + (((size_t)(4 * w + s) * 32 + kt) << 9)
                                        + lane * 8);
#pragma unroll
            for (int s = 0; s < 4; ++s)
                z[s] = __builtin_amdgcn_mfma_f32_32x32x16_f16(A, Bf[s], z[s], 0, 0, 0);
        }

        // ---- gemm1 epilogue: z = relu(z - t_b); na2 += z^2 (fp32, in-register)
#pragma unroll
        for (int reg = 0; reg < 16; ++reg) {
            const int rr = (reg & 3) + 8 * (reg >> 2) + 4 * lh;
            const float tb = tcoef * sqrtf(t2s[rr]);
            float ns = 0.f;
#pragma unroll
            for (int s = 0; s < 4; ++s) {
                float val = fmaxf(z[s][reg] - tb, 0.f);
                z[s][reg] = val;
                ns = fmaf(val, val, ns);
            }
            if (it < 9) {
                ns += __shfl_down(ns, 16, 32);
                ns += __shfl_down(ns, 8, 32);
                ns += __shfl_down(ns, 4, 32);
                ns += __shfl_down(ns, 2, 32);
                ns += __shfl_down(ns, 1, 32);
                if (ln == 0) atomicAdd(&na2[rr], ns);
            }
        }

        if (it == 9) break;               // uniform: all threads exit loop together

        __syncthreads();                  // S1: na2 complete; t2s reads done
        if (tid < 32) t2s[tid] = 0.f;

        // ---- gemm2 C-init: a2 = y + (sqrt(na2)/512) * (beta*v_old)
        floatx16 a2;
        {
            const int m = (w << 5) + ln;  // wave owns m [32w, 32w+32)
            const float* yc = y + (size_t)b0 * Msz + m;
#pragma unroll
            for (int reg = 0; reg < 16; ++reg) {
                const int rr = (reg & 3) + 8 * (reg >> 2) + 4 * lh;
                const float cb = sqrtf(na2[rr]) * (1.0f / 512.0f);
                const float vold = (float)v_lds[(m >> 4) * 512 + ((m >> 3) & 1) * 256
                                                + rr * 8 + (m & 7)];
                a2[reg] = yc[(size_t)rr * Msz] + cb * vold;
            }
        }

        // ---- alpha half 0 (n < 1024): waves 0..7 write f16(-beta*z)
        if (w < 8) {
#pragma unroll
            for (int s = 0; s < 4; ++s)
#pragma unroll
                for (int reg = 0; reg < 16; ++reg) {
                    const int rr = (reg & 3) + 8 * (reg >> 2) + 4 * lh;
                    const int n = (w << 7) + (s << 5) + ln;
                    alpha_lds[(n >> 4) * 512 + ((n >> 3) & 1) * 256 + rr * 8 + (n & 7)]
                        = (_Float16)(-beta * z[s][reg]);
                }
        }
        __syncthreads();                  // S2: half0 visible; na2 readers done
        if (tid < 32) na2[tid] = 0.f;

        // ---- gemm2 K-loop, kt 0..63  (a2 -= beta * alpha @ D^T, first half)
        for (int kt = 0; kt < 64; ++kt) {
            half8 A = *(const half8*)(alpha_lds + kt * 512 + lane * 8);
            half8 Bf = *(const half8*)(Dp + (((size_t)w * 128 + kt) << 9) + lane * 8);
            a2 = __builtin_amdgcn_mfma_f32_32x32x16_f16(A, Bf, a2, 0, 0, 0);
        }
        __syncthreads();                  // S3: half0 reads done

        // ---- alpha half 1 (n >= 1024): waves 8..15
        if (w >= 8) {
#pragma unroll
            for (int s = 0; s < 4; ++s)
#pragma unroll
                for (int reg = 0; reg < 16; ++reg) {
                    const int rr = (reg & 3) + 8 * (reg >> 2) + 4 * lh;
                    const int n = (w << 7) + (s << 5) + ln;          // 1024..2047
                    alpha_lds[((n >> 4) - 64) * 512 + ((n >> 3) & 1) * 256
                              + rr * 8 + (n & 7)]
                        = (_Float16)(-beta * z[s][reg]);
                }
        }
        __syncthreads();                  // S4: half1 visible
        for (int kt = 64; kt < 128; ++kt) {
            half8 A = *(const half8*)(alpha_lds + (kt - 64) * 512 + lane * 8);
            half8 Bf = *(const half8*)(Dp + (((size_t)w * 128 + kt) << 9) + lane * 8);
            a2 = __builtin_amdgcn_mfma_f32_32x32x16_f16(A, Bf, a2, 0, 0, 0);
        }

        // ---- gemm2 epilogue: v_new = a2; v_lds = f16(beta*v_new); t2s += (bv)^2
        {
            const int m = (w << 5) + ln;
#pragma unroll
            for (int reg = 0; reg < 16; ++reg) {
                const int rr = (reg & 3) + 8 * (reg >> 2) + 4 * lh;
                const float bv = beta * a2[reg];
                v_lds[(m >> 4) * 512 + ((m >> 3) & 1) * 256 + rr * 8 + (m & 7)] =
                    (_Float16)bv;
                float ts = bv * bv;
                ts += __shfl_down(ts, 16, 32);
                ts += __shfl_down(ts, 8, 32);
                ts += __shfl_down(ts, 4, 32);
                ts += __shfl_down(ts, 2, 32);
                ts += __shfl_down(ts, 1, 32);
                if (ln == 0) atomicAdd(&t2s[rr], ts);
            }
        }
        __syncthreads();                  // S5: v_lds + t2s ready for next iter
    }

    // ---- output: alpha fp32, plain [B][N] layout (coalesced 128B per (s,reg))
#pragma unroll
    for (int s = 0; s < 4; ++s)
#pragma unroll
        for (int reg = 0; reg < 16; ++reg) {
            const int rr = (reg & 3) + 8 * (reg >> 2) + 4 * lh;
            out[(size_t)(b0 + rr) * Nsz + (w << 7) + (s << 5) + ln] = z[s][reg];
        }
}

extern "C" void kernel_launch(void* const* d_in, const int* in_sizes, int n_in,
                              void* d_out, int out_size, void* d_ws, size_t ws_size,
                              hipStream_t stream) {
    (void)in_sizes; (void)n_in; (void)out_size; (void)ws_size;
    const float* batch   = (const float*)d_in[0];   // [B, M]
    const float* D       = (const float*)d_in[1];   // [M, N]
    const float* gamma_p = (const float*)d_in[2];   // scalar
    const float* beta_p  = (const float*)d_in[3];   // scalar

    // workspace: 4 MB (two permuted f16 D planes)
    _Float16* Dph  = (_Float16*)d_ws;               // [M*N] (gemm2 B, K=2048)
    _Float16* Dtph = Dph + (size_t)Msz * Nsz;       // [N*M] (gemm1 B, K=512)

    convD_kernel<<<dim3(Nsz / 64, Msz / 64), 256, 0, stream>>>(D, Dph, Dtph);
    amp_kernel<<<Bsz / 32, 1024, 0, stream>>>(batch, Dtph, Dph,
                                              beta_p, gamma_p, (float*)d_out);
}

// Round 10
// 1625.542 us; speedup vs baseline: 3.2796x; 3.2796x over previous
//
#include <hip/hip_runtime.h>
#include <math.h>

#define Bsz 16384
#define Msz 512
#define Nsz 2048

typedef _Float16 half8 __attribute__((ext_vector_type(8)));
typedef _Float16 half4 __attribute__((ext_vector_type(4)));
typedef _Float16 half2v __attribute__((ext_vector_type(2)));
typedef float floatx16 __attribute__((ext_vector_type(16)));
typedef unsigned int uint;

struct HL { _Float16 h, l; };
__device__ __forceinline__ HL split1(float x) {
    HL r;
    r.h = (_Float16)x;
    r.l = (_Float16)(x - (float)r.h);   // exact residual (two-term split)
    return r;
}
__device__ __forceinline__ uint packHL(float x) {
    HL s = split1(x);
    return (uint)__builtin_bit_cast(unsigned short, s.h)
         | ((uint)__builtin_bit_cast(unsigned short, s.l) << 16);
}
__device__ __forceinline__ float unpackHL(uint w) {
    half2v p = __builtin_bit_cast(half2v, w);
    return (float)p.x + (float)p.y;
}

// async global->LDS, 16B per lane. LDS dest = wave-uniform base + lane*16.
__device__ __forceinline__ void gl_lds16(const _Float16* g, _Float16* l) {
    __builtin_amdgcn_global_load_lds(
        (const __attribute__((address_space(1))) unsigned int*)g,
        (__attribute__((address_space(3))) unsigned int*)l, 16, 0, 0);
}

// raw barrier: no compiler-inserted vmcnt(0) drain (unlike __syncthreads).
#define BAR()  asm volatile("s_barrier" ::: "memory")

// fragment-permuted layout (32x32x16 MFMA), lane-linear (bank-conflict-free):
// element (r,k) of [R][K] at frag((r>>5)*(K/16) + (k>>4))*512
//                          + ((k>>3)&1)*256 + (r&31)*8 + (k&7)      [halves]
// => lane l's half8 operand (r=l&31, k=(l>>5)*8 ..+7) sits at frag*512 + l*8:
//    a wave's ds_read_b128 covers 1KB contiguous -> all 32 banks, conflict-free.
// NOTE frag-row stride = K/16: 32 for K=512 planes (Av, Dtph, vh), 128 for
// K=2048 plane (Dph).

// zero 19*Bsz floats (t2 slabs 1..9 + na2 slabs 0..9, contiguous)
__global__ __launch_bounds__(256) void zero_kernel(float4* __restrict__ p) {
    p[blockIdx.x * 256 + threadIdx.x] = make_float4(0.f, 0.f, 0.f, 0.f);
}

// iter-0: v = batch -> single f16 permuted plane; t2s[0][b] = sum(v^2) (fp32).
__global__ __launch_bounds__(256) void init_kernel(const float* __restrict__ batch,
        _Float16* __restrict__ vh, float* __restrict__ t2) {
    const int wave = threadIdx.x >> 6;
    const int lane = threadIdx.x & 63;
    const int b = (blockIdx.x << 2) + wave;
    const float* row = batch + (size_t)b * Msz + lane * 8;
    float4 a = *(const float4*)row;
    float4 c = *(const float4*)(row + 4);
    half8 h;
    h[0] = (_Float16)a.x; h[1] = (_Float16)a.y;
    h[2] = (_Float16)a.z; h[3] = (_Float16)a.w;
    h[4] = (_Float16)c.x; h[5] = (_Float16)c.y;
    h[6] = (_Float16)c.z; h[7] = (_Float16)c.w;
    // m = lane*8: frag col = lane>>1, (k>>3)&1 = lane&1, k&7 = 0
    const size_t off = ((size_t)(b >> 5) * 32 + (lane >> 1)) * 512
                     + ((size_t)(lane & 1) << 8) + ((b & 31) << 3);
    *(half8*)(vh + off) = h;
    float s = a.x*a.x + a.y*a.y + a.z*a.z + a.w*a.w
            + c.x*c.x + c.y*c.y + c.z*c.z + c.w*c.w;
#pragma unroll
    for (int off2 = 32; off2 > 0; off2 >>= 1) s += __shfl_down(s, off2);
    if (lane == 0) t2[b] = s;
}

// One-time: D [M][N] fp32 -> Dph  (gemm2 B: r=m, k=n, K=2048) single f16 plane
//                        and Dtph (gemm1 B: r=n, k=m, K=512)  single f16 plane
__global__ __launch_bounds__(256) void convD_kernel(const float* __restrict__ D,
        _Float16* __restrict__ Dph, _Float16* __restrict__ Dtph) {
    __shared__ float T[64][65];
    const int t = threadIdx.x;
    const int tx = t & 15, ty = t >> 4;
    const int n0 = blockIdx.x << 6, m0 = blockIdx.y << 6;
#pragma unroll
    for (int q = 0; q < 4; ++q) {
        const int mr = m0 + (ty << 2) + q;
        const int nc = n0 + (tx << 2);
        float4 d = *(const float4*)(D + (size_t)mr * Nsz + nc);
        half4 h;
        h[0] = (_Float16)d.x; h[1] = (_Float16)d.y;
        h[2] = (_Float16)d.z; h[3] = (_Float16)d.w;
        // r=mr, k=nc: frag-row stride 128 (K=2048)
        const size_t o2 = ((size_t)(mr >> 5) * 128 + (nc >> 4)) * 512
                        + (((size_t)(nc >> 3) & 1) << 8) + ((mr & 31) << 3) + (nc & 7);
        *(half4*)(Dph + o2) = h;
        T[(tx << 2) + 0][(ty << 2) + q] = d.x;
        T[(tx << 2) + 1][(ty << 2) + q] = d.y;
        T[(tx << 2) + 2][(ty << 2) + q] = d.z;
        T[(tx << 2) + 3][(ty << 2) + q] = d.w;
    }
    __syncthreads();
#pragma unroll
    for (int q = 0; q < 4; ++q) {
        const int nr = n0 + (ty << 2) + q;
        const int mc = m0 + (tx << 2);
        float4 d = make_float4(T[(ty << 2) + q][tx << 2],
                               T[(ty << 2) + q][(tx << 2) + 1],
                               T[(ty << 2) + q][(tx << 2) + 2],
                               T[(ty << 2) + q][(tx << 2) + 3]);
        half4 h;
        h[0] = (_Float16)d.x; h[1] = (_Float16)d.y;
        h[2] = (_Float16)d.z; h[3] = (_Float16)d.w;
        // r=nr, k=mc: frag-row stride 32 (K=512)
        const size_t o1 = ((size_t)(nr >> 5) * 32 + (mc >> 4)) * 512
                        + (((size_t)(mc >> 3) & 1) << 8) + ((nr & 31) << 3) + (mc & 7);
        *(half4*)(Dtph + o1) = h;
    }
}

// gemm1: alpha = relu((FIRST?0:alpha) + beta*(v@D) - t[b]); fused na2 atomic.
// 128x128 tile, 4 waves (2x2), 16KB single-buffer LDS, BK=32 (16 chunks),
// stage->drain->compute, 4 resident blocks/CU (pinned by 120 unified regs).
// FIRST/LAST as template params: no per-element runtime branches in epilogue.
template<int FIRST, int LAST>
__global__ __launch_bounds__(256, 4) void gemm1_kernel(
        const _Float16* __restrict__ Av,
        const _Float16* __restrict__ Bth,
        const float* __restrict__ t2,
        uint* __restrict__ alphaP,
        float* __restrict__ na2,
        const float* __restrict__ beta_p, const float* __restrict__ gamma_p) {
    __shared__ _Float16 lds[8192];    // 16KB: A frags 0..7 | B frags 8..15

    const int tid = threadIdx.x;
    const int wave = tid >> 6, lane = tid & 63;
    const int wy = wave >> 1, wx = wave & 1;     // 2x2 wave grid
    const int ln = lane & 31, lh = lane >> 5;
    const int bid = blockIdx.x;
    const int b0 = (bid & 127) << 7;             // 128 row-tiles of 128
    const int n0 = (bid >> 7) << 7;              // 16 col-tiles of 128
    const int R0 = b0 >> 5, C0 = n0 >> 5;

    floatx16 acc[2][2] = {};

    // staging: 16 frags/chunk, 4 per wave. frag f<8: A subtile f>>1, ktile f&1;
    // f>=8: B subtile (f-8)>>1, ktile (f-8)&1. Both planes K=512 -> stride 32.
    const _Float16* pb[4];
#pragma unroll
    for (int e = 0; e < 4; ++e) {
        const int f = wave * 4 + e;
        const bool isB = f >= 8;
        const int q = isB ? f - 8 : f;
        const int t = q >> 1, kt = q & 1;
        const _Float16* base = isB ? Bth : Av;
        const int T0 = isB ? C0 : R0;
        pb[e] = base + ((size_t)(T0 + t) * 32) * 512 + (size_t)kt * 512 + lane * 8;
    }
    const int f0 = wave * 4;

    const int ro = lane << 3;            // lane-linear fragment read offset (halves)

    for (int c = 0; c < 16; ++c) {       // BK=32
        __syncthreads();                 // previous chunk's frag reads done
#pragma unroll
        for (int e = 0; e < 4; ++e)
            gl_lds16(pb[e] + (size_t)c * 1024, lds + ((f0 + e) << 9));
        __builtin_amdgcn_s_waitcnt(0);   // drain this wave's DMA
        __syncthreads();                 // all frags staged

#pragma unroll
        for (int ks = 0; ks < 2; ++ks) {
            half8 fa[2], fb[2];
#pragma unroll
            for (int i = 0; i < 2; ++i) {
                fa[i] = *(const half8*)(lds + ((((wy * 2 + i) << 1) + ks) << 9) + ro);
                fb[i] = *(const half8*)(lds + 4096 + ((((wx * 2 + i) << 1) + ks) << 9) + ro);
            }
#pragma unroll
            for (int j = 0; j < 2; ++j)
#pragma unroll
                for (int i = 0; i < 2; ++i)
                    acc[i][j] = __builtin_amdgcn_mfma_f32_32x32x16_f16(fa[i], fb[j], acc[i][j], 0, 0, 0);
        }
    }

    const float beta = beta_p[0];
    const float tc = gamma_p[0] * 0.044194173824159216f;   // gamma / sqrt(512)
#pragma unroll
    for (int i = 0; i < 2; ++i) {
#pragma unroll
        for (int reg = 0; reg < 16; ++reg) {
            const int rr = (reg & 3) + 8 * (reg >> 2) + 4 * lh;   // 0..31
            const int b = b0 + wy * 64 + i * 32 + rr;
            const float tb2 = tc * sqrtf(t2[b]);
            uint* arow = alphaP + (size_t)b * Nsz + n0 + wx * 64 + ln;
            float s = 0.f;
#pragma unroll
            for (int j = 0; j < 2; ++j) {
                float z = FIRST ? 0.f : unpackHL(arow[j * 32]);
                float val = fmaxf(fmaf(beta, acc[i][j][reg], z) - tb2, 0.f);
                if (LAST) ((float*)arow)[j * 32] = val;   // final fp32, same 4-B slot
                else      arow[j * 32] = packHL(val);
                s = fmaf(val, val, s);
            }
            s += __shfl_down(s, 16, 32);
            s += __shfl_down(s, 8, 32);
            s += __shfl_down(s, 4, 32);
            s += __shfl_down(s, 2, 32);
            s += __shfl_down(s, 1, 32);
            if (ln == 0) atomicAdd(&na2[b], s);
        }
    }
}

// gemm2: v = y - beta*(alpha@D^T) + beta/512*sqrt(na2[b])*v_old; fused t2 atomic.
// 128x128 tile, 4 waves (2x2), grid 512 = 2 blocks/CU. Double-buffered 32KB,
// counted vmcnt (never 0 mid-loop), raw barriers. A = alpha_hi regs
// (load c+3, write c+2); B via gl_lds (2 frags/wave).
__global__ __launch_bounds__(256, 2) void gemm2_kernel(
        const uint* __restrict__ alphaP,
        const _Float16* __restrict__ Bh,
        const float* __restrict__ na2,
        const float* __restrict__ y,
        _Float16* __restrict__ vh,
        float* __restrict__ t2,
        const float* __restrict__ beta_p) {
    __shared__ _Float16 lds[16384];   // 32KB: 2 x (A frags 0..7 | B frags 8..15)

    const int tid = threadIdx.x;
    const int wave = tid >> 6, lane = tid & 63;
    const int wy = wave >> 1, wx = wave & 1;
    const int ln = lane & 31, lh = lane >> 5;
    const int bid = blockIdx.x;
    const int b0 = (bid & 127) << 7;             // 128 row-tiles of 128
    const int m0 = (bid >> 7) << 7;              // 4 col-tiles of 128
    const int C0 = m0 >> 5;

    floatx16 acc[2][2] = {};

    // A staging: thread (srow, skq) covers one ktile-half of one row (16 words)
    const int srow = tid >> 1;                   // 0..127
    const int skq  = (tid & 1) << 4;
    const uint* apP = alphaP + (size_t)(b0 + srow) * Nsz + skq;
    // lane-linear frag layout: k&15 in 0..7 -> +0, 8..15 -> +256
    const int awo = ((((srow >> 5) << 1) + (skq >> 4)) << 9) + ((srow & 31) << 3);

    // B staging via gl_lds: wave w stages B subtile C0+w, both ktiles.
    // Dph frag-row stride = K/16 = 128 (K=2048).
    const _Float16* gB = Bh + ((size_t)(C0 + wave) * 128) * 512 + lane * 8;
    const int fB = 8 + wave * 2;

    const int ro = lane << 3;

    uint4 a0, a1, a2, a3;
    auto loadA = [&](int c) {
        const uint* nx = apP + c * 32;
        a0 = *(const uint4*)(nx);
        a1 = *(const uint4*)(nx + 4);
        a2 = *(const uint4*)(nx + 8);
        a3 = *(const uint4*)(nx + 12);
    };
    auto writeA = [&](int d) {      // extract hi (low16s) and ds_write in frag format
        uint4 ha, hb;
        ha.x = __builtin_amdgcn_perm(a0.y, a0.x, 0x05040100u);
        ha.y = __builtin_amdgcn_perm(a0.w, a0.z, 0x05040100u);
        ha.z = __builtin_amdgcn_perm(a1.y, a1.x, 0x05040100u);
        ha.w = __builtin_amdgcn_perm(a1.w, a1.z, 0x05040100u);
        hb.x = __builtin_amdgcn_perm(a2.y, a2.x, 0x05040100u);
        hb.y = __builtin_amdgcn_perm(a2.w, a2.z, 0x05040100u);
        hb.z = __builtin_amdgcn_perm(a3.y, a3.x, 0x05040100u);
        hb.w = __builtin_amdgcn_perm(a3.w, a3.z, 0x05040100u);
        _Float16* aw = lds + d * 8192 + awo;
        *(uint4*)aw = ha;
        *(uint4*)(aw + 256) = hb;
    };
    auto stageB = [&](int c, int d) {
        _Float16* lB = lds + d * 8192;
#pragma unroll
        for (int kt = 0; kt < 2; ++kt)
            gl_lds16(gB + (size_t)kt * 512 + (size_t)c * 1024, lB + ((fB + kt) << 9));
    };

    // prologue: buf0 complete; buf1 B in flight + A written; regs hold A(2)
    loadA(0);
    writeA(0);
    stageB(0, 0);
    loadA(1);
    writeA(1);            // implicit vmcnt wait drains loadA(1) (and stageB(0))
    stageB(1, 1);
    loadA(2);
    asm volatile("s_waitcnt vmcnt(6) lgkmcnt(0)" ::: "memory");
    BAR();

    for (int c = 0; c < 64; ++c) {
        const _Float16* lb = lds + (c & 1) * 8192;
        __builtin_amdgcn_s_setprio(1);
#pragma unroll
        for (int ks = 0; ks < 2; ++ks) {
            half8 fa[2], fb[2];
#pragma unroll
            for (int i = 0; i < 2; ++i) {
                fa[i] = *(const half8*)(lb + ((((wy * 2 + i) << 1) + ks) << 9) + ro);
                fb[i] = *(const half8*)(lb + 4096 + ((((wx * 2 + i) << 1) + ks) << 9) + ro);
            }
#pragma unroll
            for (int j = 0; j < 2; ++j)
#pragma unroll
                for (int i = 0; i < 2; ++i)
                    acc[i][j] = __builtin_amdgcn_mfma_f32_32x32x16_f16(fa[i], fb[j], acc[i][j], 0, 0, 0);
        }
        __builtin_amdgcn_s_setprio(0);
        if (c == 63) break;
        BAR();                           // readers of buf[c&1] done
        if (c < 61) {
            stageB(c + 2, c & 1);        // B(c+2) flies across barriers
            writeA(c & 1);               // A(c+2); implicit wait drains loadA(c+2)
            loadA(c + 3);                // A regs for next chunk's writeA
            asm volatile("s_waitcnt vmcnt(6) lgkmcnt(0)" ::: "memory");
        } else if (c == 61) {
            stageB(63, 1);
            writeA(1);                   // A(63) from loadA(63) (issued at c=60)
            asm volatile("s_waitcnt vmcnt(2) lgkmcnt(0)" ::: "memory");
        } else {                         // c == 62: drain stageB(63)
            asm volatile("s_waitcnt vmcnt(0) lgkmcnt(0)" ::: "memory");
        }
        BAR();                           // buf[(c+1)&1] published
    }

    const float beta = beta_p[0];
#pragma unroll
    for (int i = 0; i < 2; ++i) {
#pragma unroll
        for (int reg = 0; reg < 16; ++reg) {
            const int rr = (reg & 3) + 8 * (reg >> 2) + 4 * lh;
            const int b = b0 + wy * 64 + i * 32 + rr;
            const float cb = beta * (1.0f / 512.0f) * sqrtf(na2[b]);
            float s = 0.f;
#pragma unroll
            for (int j = 0; j < 2; ++j) {
                const int m = m0 + wx * 64 + j * 32 + ln;
                const size_t po = ((size_t)(b >> 5) * 32 + (m >> 4)) * 512
                                + (((size_t)(m >> 3) & 1) << 8) + ((b & 31) << 3) + (m & 7);
                const size_t yi = (size_t)b * Msz + m;
                float vold = (float)vh[po];
                float val = y[yi] - beta * acc[i][j][reg] + cb * vold;
                vh[po] = (_Float16)val;
                s = fmaf(val, val, s);
            }
            s += __shfl_down(s, 16, 32);
            s += __shfl_down(s, 8, 32);
            s += __shfl_down(s, 4, 32);
            s += __shfl_down(s, 2, 32);
            s += __shfl_down(s, 1, 32);
            if (ln == 0) atomicAdd(&t2[b], s);
        }
    }
}

extern "C" void kernel_launch(void* const* d_in, const int* in_sizes, int n_in,
                              void* d_out, int out_size, void* d_ws, size_t ws_size,
                              hipStream_t stream) {
    (void)in_sizes; (void)n_in; (void)out_size; (void)ws_size;
    const float* batch   = (const float*)d_in[0];   // [B, M]
    const float* D       = (const float*)d_in[1];   // [M, N]
    const float* gamma_p = (const float*)d_in[2];   // scalar
    const float* beta_p  = (const float*)d_in[3];   // scalar

    uint* alphaP = (uint*)d_out;    // packed hi/lo per element (plain layout); fp32 after final iter

    // workspace (~22 MB)
    _Float16* vh   = (_Float16*)d_ws;               // [B*M] permuted, single plane
    _Float16* Dph  = vh + (size_t)Bsz * Msz;        // [M*N] permuted (gemm2 B), f16
    _Float16* Dtph = Dph + (size_t)Msz * Nsz;       // [N*M] permuted (gemm1 B), f16
    float*    t2s  = (float*)(Dtph + (size_t)Msz * Nsz);   // [10][Bsz] sum v^2
    float*    na2s = t2s + 10 * Bsz;                        // [10][Bsz] sum alpha^2

    // zero t2 slabs 1..9 + na2 slabs 0..9 (contiguous 19*Bsz floats)
    zero_kernel<<<19 * Bsz / 1024, 256, 0, stream>>>((float4*)(t2s + Bsz));
    convD_kernel<<<dim3(Nsz / 64, Msz / 64), 256, 0, stream>>>(D, Dph, Dtph);
    init_kernel<<<Bsz / 4, 256, 0, stream>>>(batch, vh, t2s);   // writes t2 slab 0

    for (int it = 0; it < 10; ++it) {
        if (it == 0)
            gemm1_kernel<1, 0><<<2048, 256, 0, stream>>>(vh, Dtph,
                    t2s + (size_t)it * Bsz, alphaP, na2s + (size_t)it * Bsz,
                    beta_p, gamma_p);
        else if (it == 9)
            gemm1_kernel<0, 1><<<2048, 256, 0, stream>>>(vh, Dtph,
                    t2s + (size_t)it * Bsz, alphaP, na2s + (size_t)it * Bsz,
                    beta_p, gamma_p);
        else
            gemm1_kernel<0, 0><<<2048, 256, 0, stream>>>(vh, Dtph,
                    t2s + (size_t)it * Bsz, alphaP, na2s + (size_t)it * Bsz,
                    beta_p, gamma_p);
        if (it < 9) {   // last iteration's new_v is unused by the reference output
            gemm2_kernel<<<512, 256, 0, stream>>>(alphaP, Dph,
                                                  na2s + (size_t)it * Bsz,
                                                  batch, vh,
                                                  t2s + (size_t)(it + 1) * Bsz,
                                                  beta_p);
        }
    }
}